// Round 1
// 1734.501 us; speedup vs baseline: 1.0361x; 1.0361x over previous
//
#include <hip/hip_runtime.h>
#include <stdint.h>

// ---------------------------------------------------------------------------
// RelationAttention on MI355X (gfx950), bf16-MFMA pipeline.
//
// Stages (all on `stream`, graph-capture safe):
//   1) cast first_app / second_app fp32 -> bf16            (ws: Afs, Asnd)
//   2) transpose-cast Wk/Wq/Wv fp32[K][N] -> bf16[N][K]    (ws: WkT,WqT,WvT)
//   3a) gemm_kq (256x256 8-phase template): K = A@Wk+bk and Q = S@Wq+bq in ONE
//       dispatch, selected by blockIdx.z. grid (32,4,2) = 256 blocks = 1/CU.
//   3b) gemm_bt (m97 pattern): V = A@Wv+bv (N=256 only)
//   4) normalize Q rows per (b,m,h) over 256 dims
//   5) fused attention: S = Qn K^T / 256; softmax WITHOUT max-subtraction
//      (logits |s| <= ~0.14 provably -> exp safe); O = P V; out = O / l.
//
// Workspace layout (needs ~507 MB):
//   Afs  @ 0          : 8192*12544 bf16
//   Asnd @ 205520896  : 8192*12544 bf16
//   WkT  @ 411041792  : 1024*12544 bf16
//   WqT  @ 436731904  : 1024*12544 bf16
//   WvT  @ 462422016  :  256*12544 bf16
//   Kw   @ 468844544  : 8192*1024  bf16   [B,N,H,MD]
//   Qw   @ 485621760  : 8192*1024  bf16   [B,M,H,MD]
//   Vw   @ 502398976  : 8192*256   bf16   [B,N,H,DV]
// ---------------------------------------------------------------------------

typedef __bf16 bf16;
typedef __bf16 bf16x4 __attribute__((ext_vector_type(4)));
typedef __bf16 bf16x8 __attribute__((ext_vector_type(8)));
typedef float  f32x4  __attribute__((ext_vector_type(4)));

__device__ __forceinline__ void async_ld16(const void* g, void* lds) {
  // global -> LDS direct, 16B/lane. LDS dest is wave-uniform base + lane*16.
  __builtin_amdgcn_global_load_lds(
      (__attribute__((address_space(1))) void*)(g),
      (__attribute__((address_space(3))) void*)(lds), 16, 0, 0);
}

// -------------------------------- 1) cast ----------------------------------
__global__ __launch_bounds__(256) void cast_bf16_kernel(
    const float4* __restrict__ in, bf16x4* __restrict__ out, int n4) {
  int i0 = blockIdx.x * blockDim.x + threadIdx.x;
  int stride = gridDim.x * blockDim.x;
  for (int i = i0; i < n4; i += stride) {
    float4 v = in[i];
    bf16x4 o;
    o[0] = (bf16)v.x; o[1] = (bf16)v.y; o[2] = (bf16)v.z; o[3] = (bf16)v.w;
    out[i] = o;
  }
}

// --------------------------- 2) transpose-cast -----------------------------
// W fp32 [K=12544][N] -> WT bf16 [N][12544].  64x64 tiles via LDS.
__global__ __launch_bounds__(256) void transpose_cast_kernel(
    const float* __restrict__ W, bf16* __restrict__ WT, int N) {
  __shared__ __align__(16) bf16 tile[64 * 76];  // pad 76 to soften conflicts
  const int k0 = blockIdx.x * 64;
  const int n0 = blockIdx.y * 64;
  const int t = threadIdx.x;
  const int tr = t >> 4, tc = t & 15;
#pragma unroll
  for (int rnd = 0; rnd < 4; ++rnd) {
    int r = rnd * 16 + tr;  // local k
    float4 v = *(const float4*)(W + (size_t)(k0 + r) * N + n0 + tc * 4);
    bf16x4 o;
    o[0] = (bf16)v.x; o[1] = (bf16)v.y; o[2] = (bf16)v.z; o[3] = (bf16)v.w;
    *(bf16x4*)&tile[r * 76 + tc * 4] = o;
  }
  __syncthreads();
#pragma unroll
  for (int rnd = 0; rnd < 4; ++rnd) {
    int rr = rnd * 16 + tr;  // local n
    int c0 = tc * 4;         // local k
    bf16x4 o;
    o[0] = tile[(c0 + 0) * 76 + rr];
    o[1] = tile[(c0 + 1) * 76 + rr];
    o[2] = tile[(c0 + 2) * 76 + rr];
    o[3] = tile[(c0 + 3) * 76 + rr];
    *(bf16x4*)(WT + (size_t)(n0 + rr) * 12544 + k0 + c0) = o;
  }
}

// --------------------- 3a) fused K/Q GEMM, 8-phase 256^2 -------------------
// C[8192][1024] = A[8192][12544] * Bt[1024][12544]^T + bias, bf16 out.
// blockIdx.z selects (A,Bt,bias,C) = (Afs,WkT,bk,Kw) or (Asnd,WqT,bq,Qw).
// 256x256 tile, BK=64, 512 threads = 8 waves (2M x 4N), per-wave out 128x64.
// LDS 128KB: double-buffered A/B tiles, XOR chunk-swizzle (8-elem chunks,
// LDS chunk cb' of row m holds global chunk cb'^(m&7)); global_load_lds
// staging with linear dest + pre-swizzled source.
// Per K-tile: 4 phases, each = one C-quadrant (64x32 of the wave's 128x64)
//   { 12 ds_read_b128 | prefetch-issue (phases 0,1) | s_barrier |
//     setprio(1) 16x MFMA setprio(0) | s_barrier }
// Single vmcnt wait per tile at the boundary; the 8 prefetch loads were
// issued >=3 phases earlier, so they retire without stalling (loads stay in
// flight across the intra-tile barriers -> T3+T4).
__global__ __launch_bounds__(512, 2) void gemm_kq_kernel(
    const bf16* __restrict__ Afs, const bf16* __restrict__ Asnd,
    const bf16* __restrict__ WkT, const bf16* __restrict__ WqT,
    const float* __restrict__ bk, const float* __restrict__ bq,
    bf16* __restrict__ Kw, bf16* __restrict__ Qw) {
  __shared__ __align__(16) bf16 As[2][256 * 64];
  __shared__ __align__(16) bf16 Bs[2][256 * 64];
  const int z = blockIdx.z;
  const bf16* __restrict__ A    = z ? Asnd : Afs;
  const bf16* __restrict__ Bt   = z ? WqT : WkT;
  const float* __restrict__ bias = z ? bq : bk;
  bf16* __restrict__ C = z ? Qw : Kw;

  const size_t K = 12544;
  const int tid = threadIdx.x;
  const int w = tid >> 6, l = tid & 63;
  const int wr = w >> 2, wc = w & 3;        // 2 M-waves x 4 N-waves
  const int quad = l >> 4, lo = l & 15;
  const size_t rowT = (size_t)blockIdx.x * 256;
  const size_t colT = (size_t)blockIdx.y * 256;

  // staging map: thread t covers row-in-issue srow = t>>3 (issue = 64 rows),
  // LDS chunk slot t&7; global chunk fetched = (t&7)^(srow&7) so that a
  // linear LDS write realizes the XOR swizzle.
  const int srow = tid >> 3;
  const int scb = (tid & 7) ^ (srow & 7);
  const bf16* Ag = A + (rowT + srow) * K + scb * 8;
  const bf16* Bg = Bt + (colT + srow) * K + scb * 8;
  const int ldsw = w * 8 * 64;  // wave-uniform LDS base offset within an issue

#define STAGE_A(i, d_, kofs) \
  async_ld16(Ag + (size_t)(i) * 64 * K + (kofs), &As[d_][(i) * 64 * 64 + ldsw])
#define STAGE_B(i, d_, kofs) \
  async_ld16(Bg + (size_t)(i) * 64 * K + (kofs), &Bs[d_][(i) * 64 * 64 + ldsw])

  f32x4 acc[8][4];
#pragma unroll
  for (int mi = 0; mi < 8; ++mi)
#pragma unroll
    for (int ni = 0; ni < 4; ++ni)
#pragma unroll
      for (int r = 0; r < 4; ++r) acc[mi][ni][r] = 0.0f;

  // prologue: stage tile 0 into buffer 0
#pragma unroll
  for (int i = 0; i < 4; ++i) STAGE_A(i, 0, 0);
#pragma unroll
  for (int i = 0; i < 4; ++i) STAGE_B(i, 0, 0);
  asm volatile("s_waitcnt vmcnt(0)" ::: "memory");
  __builtin_amdgcn_s_barrier();

  for (int kt = 0; kt < 196; ++kt) {
    const int d = kt & 1;
    const int knext = (kt + 1) * 64;
    const bool pf = kt < 195;
#pragma unroll
    for (int q = 0; q < 4; ++q) {
      const int mq = q >> 1, nq = q & 1;
      // register subtile for this quadrant (12 x ds_read_b128)
      bf16x8 af[4][2], bfr[2][2];
#pragma unroll
      for (int a = 0; a < 4; ++a) {
        const int m = wr * 128 + (mq * 4 + a) * 16 + lo;
#pragma unroll
        for (int ks = 0; ks < 2; ++ks) {
          const int g = ks * 4 + quad;
          af[a][ks] = *(const bf16x8*)&As[d][m * 64 + (g ^ (m & 7)) * 8];
        }
      }
#pragma unroll
      for (int bi = 0; bi < 2; ++bi) {
        const int n = wc * 64 + (nq * 2 + bi) * 16 + lo;
#pragma unroll
        for (int ks = 0; ks < 2; ++ks) {
          const int g = ks * 4 + quad;
          bfr[bi][ks] = *(const bf16x8*)&Bs[d][n * 64 + (g ^ (n & 7)) * 8];
        }
      }
      // prefetch-issue next tile early (retires at the tile boundary, >=3
      // phases later -> latency hidden under MFMA of phases 1..3)
      if (q == 0 && pf) {
        STAGE_A(0, d ^ 1, knext); STAGE_A(1, d ^ 1, knext);
        STAGE_B(0, d ^ 1, knext); STAGE_B(1, d ^ 1, knext);
      }
      if (q == 1 && pf) {
        STAGE_A(2, d ^ 1, knext); STAGE_A(3, d ^ 1, knext);
        STAGE_B(2, d ^ 1, knext); STAGE_B(3, d ^ 1, knext);
      }
      __builtin_amdgcn_s_barrier();
      __builtin_amdgcn_s_setprio(1);
#pragma unroll
      for (int ks = 0; ks < 2; ++ks)
#pragma unroll
        for (int a = 0; a < 4; ++a)
#pragma unroll
          for (int bi = 0; bi < 2; ++bi)
            acc[mq * 4 + a][nq * 2 + bi] = __builtin_amdgcn_mfma_f32_16x16x32_bf16(
                af[a][ks], bfr[bi][ks], acc[mq * 4 + a][nq * 2 + bi], 0, 0, 0);
      __builtin_amdgcn_s_setprio(0);
      if (q < 3) {
        __builtin_amdgcn_s_barrier();
      } else {
        // tile boundary: retire next-tile staging (old loads -> no stall),
        // then release both buffers for the next iteration.
        asm volatile("s_waitcnt vmcnt(0)" ::: "memory");
        __builtin_amdgcn_s_barrier();
      }
    }
  }
#undef STAGE_A
#undef STAGE_B

  // epilogue: +bias, bf16 store. C/D layout: col = lane&15, row = quad*4+r.
#pragma unroll
  for (int ni = 0; ni < 4; ++ni) {
    const int col = (int)colT + wc * 64 + ni * 16 + lo;
    const float bb = bias[col];
#pragma unroll
    for (int mi = 0; mi < 8; ++mi) {
#pragma unroll
      for (int r = 0; r < 4; ++r) {
        const size_t row = rowT + wr * 128 + mi * 16 + quad * 4 + r;
        C[row * 1024 + col] = (bf16)(acc[mi][ni][r] + bb);
      }
    }
  }
}

// ------------------------------ 3b) V GEMM ---------------------------------
// C[8192][N] = A[8192][12544] * Bt[N][12544]^T + bias, bf16 out. (m97 style)
__global__ __launch_bounds__(256) void gemm_bt_kernel(
    const bf16* __restrict__ A, const bf16* __restrict__ Bt,
    const float* __restrict__ bias, bf16* __restrict__ C, int N) {
  __shared__ __align__(16) bf16 As[128 * 64];
  __shared__ __align__(16) bf16 Bs[128 * 64];
  const int tid = threadIdx.x;
  const int w = tid >> 6, l = tid & 63;
  const int wr = w >> 1, wc = w & 1;
  const int quad = l >> 4, lo = l & 15;
  const size_t K = 12544;
  const size_t rowT = (size_t)blockIdx.x * 128;
  const size_t colT = (size_t)blockIdx.y * 128;
  const int srow = l >> 3;
  const int scb = (l & 7) ^ srow;
  const bf16* Ag = A + rowT * K + (size_t)scb * 8;
  const bf16* Bg = Bt + colT * K + (size_t)scb * 8;

  f32x4 acc[4][4];
#pragma unroll
  for (int mi = 0; mi < 4; ++mi)
#pragma unroll
    for (int ni = 0; ni < 4; ++ni)
#pragma unroll
      for (int r = 0; r < 4; ++r) acc[mi][ni][r] = 0.0f;

  for (int k0 = 0; k0 < 12544; k0 += 64) {
    __syncthreads();  // previous tile fully consumed
#pragma unroll
    for (int i = 0; i < 4; ++i) {
      int row = i * 32 + w * 8 + srow;
      async_ld16(Ag + (size_t)row * K + k0, &As[(i * 256 + w * 64) * 8]);
    }
#pragma unroll
    for (int i = 0; i < 4; ++i) {
      int row = i * 32 + w * 8 + srow;
      async_ld16(Bg + (size_t)row * K + k0, &Bs[(i * 256 + w * 64) * 8]);
    }
    __syncthreads();  // compiler drains vmcnt before barrier -> data ready
#pragma unroll
    for (int ks = 0; ks < 2; ++ks) {
      bf16x8 af[4], bfr[4];
#pragma unroll
      for (int mi = 0; mi < 4; ++mi) {
        int m = wr * 64 + mi * 16 + lo;
        int cb = (ks * 4 + quad) ^ (m & 7);
        af[mi] = *(const bf16x8*)&As[m * 64 + cb * 8];
      }
#pragma unroll
      for (int ni = 0; ni < 4; ++ni) {
        int n = wc * 64 + ni * 16 + lo;
        int cb = (ks * 4 + quad) ^ (n & 7);
        bfr[ni] = *(const bf16x8*)&Bs[n * 64 + cb * 8];
      }
#pragma unroll
      for (int mi = 0; mi < 4; ++mi)
#pragma unroll
        for (int ni = 0; ni < 4; ++ni)
          acc[mi][ni] = __builtin_amdgcn_mfma_f32_16x16x32_bf16(
              af[mi], bfr[ni], acc[mi][ni], 0, 0, 0);
    }
  }
#pragma unroll
  for (int ni = 0; ni < 4; ++ni) {
    int col = (int)colT + wc * 64 + ni * 16 + lo;
    float bb = bias[col];
#pragma unroll
    for (int mi = 0; mi < 4; ++mi) {
#pragma unroll
      for (int r = 0; r < 4; ++r) {
        size_t row = rowT + wr * 64 + mi * 16 + quad * 4 + r;
        C[row * (size_t)N + col] = (bf16)(acc[mi][ni][r] + bb);
      }
    }
  }
}

// --------------------------- 4) normalize Q --------------------------------
// One wave per (b,m,h) head-row of 256; L2-normalize.
__global__ __launch_bounds__(256) void normq_kernel(bf16* __restrict__ Q) {
  const int w = threadIdx.x >> 6, l = threadIdx.x & 63;
  size_t base = ((size_t)blockIdx.x * 4 + w) * 256 + l * 4;
  bf16x4 v = *(bf16x4*)(Q + base);
  float f0 = (float)v[0], f1 = (float)v[1], f2 = (float)v[2], f3 = (float)v[3];
  float ss = f0 * f0 + f1 * f1 + f2 * f2 + f3 * f3;
#pragma unroll
  for (int m = 1; m < 64; m <<= 1) ss += __shfl_xor(ss, m, 64);
  float rn = rsqrtf(ss);
  bf16x4 o;
  o[0] = (bf16)(f0 * rn); o[1] = (bf16)(f1 * rn);
  o[2] = (bf16)(f2 * rn); o[3] = (bf16)(f3 * rn);
  *(bf16x4*)(Q + base) = o;
}

// ---------------------------- 5) attention ---------------------------------
// Block = (64 q-rows) x one (b,h). 4 waves, 16 q-rows each. N-tiles of 32.
// No max-subtraction (logits tiny): l = sum exp(s), O = sum exp(s)*V, out=O/l.
__global__ __launch_bounds__(256) void attn_kernel(
    const bf16* __restrict__ Qn, const bf16* __restrict__ Kb,
    const bf16* __restrict__ Vb, float* __restrict__ out) {
  __shared__ __align__(16) bf16 Qs[64 * 256];   // swizzled, 32KB
  __shared__ __align__(16) bf16 Ks[32 * 256];   // swizzled, 16KB
  __shared__ __align__(16) bf16 Vst[64 * 40];   // V^T [v][n], pad 40
  __shared__ __align__(16) bf16 Ps[4 * 16 * 40];  // per-wave P, pad 40
  const int tid = threadIdx.x;
  const int w = tid >> 6, l = tid & 63;
  const int quad = l >> 4, lo = l & 15;
  const int m0 = blockIdx.x * 64;
  const int h = blockIdx.y, b = blockIdx.z;
  const bf16* Qg = Qn + ((size_t)b * 1024 + m0) * 1024 + h * 256;
  const bf16* Kg = Kb + (size_t)b * 1024 * 1024 + h * 256;
  const bf16* Vg = Vb + (size_t)b * 1024 * 256 + h * 64;

  // stage Q tile [64][256], swizzled (chunk cb' holds global cb'^(row&7))
  {
    int rbase = w * 2 + (l >> 5);
    int cbp = l & 31;
#pragma unroll
    for (int i = 0; i < 8; ++i) {
      int row = i * 8 + rbase;
      int cb = cbp ^ (row & 7);
      async_ld16(Qg + (size_t)row * 1024 + cb * 8, &Qs[(i * 256 + w * 64) * 8]);
    }
  }

  const int m = w * 16 + lo;  // this lane's A-frag q-row (local)
  bf16x8 af[8];
  f32x4 acc_o[4];
#pragma unroll
  for (int vi = 0; vi < 4; ++vi)
#pragma unroll
    for (int r = 0; r < 4; ++r) acc_o[vi][r] = 0.0f;
  float lsum[4] = {0.f, 0.f, 0.f, 0.f};

  for (int nt = 0; nt < 32; ++nt) {
    const int n0 = nt * 32;
    __syncthreads();  // previous tile's Ks/Vst consumed
    {
      int rbase = w * 2 + (l >> 5);
      int cbp = l & 31;
#pragma unroll
      for (int i = 0; i < 4; ++i) {
        int row = i * 8 + rbase;
        int cb = cbp ^ (row & 7);
        async_ld16(Kg + (size_t)(n0 + row) * 1024 + cb * 8,
                   &Ks[(i * 256 + w * 64) * 8]);
      }
    }
    {  // V tile transposed into Vst[v][n]
#pragma unroll
      for (int rnd = 0; rnd < 2; ++rnd) {
        int n = rnd * 16 + (tid >> 4);
        int v0 = (tid & 15) * 4;
        bf16x4 vv = *(const bf16x4*)(Vg + (size_t)(n0 + n) * 256 + v0);
#pragma unroll
        for (int j = 0; j < 4; ++j) Vst[(v0 + j) * 40 + n] = vv[j];
      }
    }
    __syncthreads();
    if (nt == 0) {  // Q frags live in registers for the whole loop
#pragma unroll
      for (int ks = 0; ks < 8; ++ks) {
        int cb = (ks * 4 + quad) ^ (m & 7);
        af[ks] = *(const bf16x8*)&Qs[m * 256 + cb * 8];
      }
    }
    // QK^T: per wave S[16 x 32]
    f32x4 acc_s[2];
#pragma unroll
    for (int ni = 0; ni < 2; ++ni)
#pragma unroll
      for (int r = 0; r < 4; ++r) acc_s[ni][r] = 0.0f;
#pragma unroll
    for (int ks = 0; ks < 8; ++ks) {
#pragma unroll
      for (int ni = 0; ni < 2; ++ni) {
        int n = ni * 16 + lo;
        int cb = (ks * 4 + quad) ^ (n & 7);
        bf16x8 bfr = *(const bf16x8*)&Ks[n * 256 + cb * 8];
        acc_s[ni] =
            __builtin_amdgcn_mfma_f32_16x16x32_bf16(af[ks], bfr, acc_s[ni], 0, 0, 0);
      }
    }
    // exp (no max needed), row-sum partials, P -> LDS in A-operand layout
#pragma unroll
    for (int ni = 0; ni < 2; ++ni) {
#pragma unroll
      for (int r = 0; r < 4; ++r) {
        float p = __expf(acc_s[ni][r] * (1.0f / 256.0f));
        lsum[r] += p;
        Ps[w * 640 + (quad * 4 + r) * 40 + ni * 16 + lo] = (bf16)p;
      }
    }
    __syncthreads();  // (safety: order Ps writes before reads)
    // PV: O[16 x 64] += P[16 x 32] * V[32 x 64]
    bf16x8 ap = *(const bf16x8*)&Ps[w * 640 + lo * 40 + quad * 8];
#pragma unroll
    for (int vi = 0; vi < 4; ++vi) {
      bf16x8 bv = *(const bf16x8*)&Vst[(vi * 16 + lo) * 40 + quad * 8];
      acc_o[vi] = __builtin_amdgcn_mfma_f32_16x16x32_bf16(ap, bv, acc_o[vi], 0, 0, 0);
    }
  }
  // reduce row sums across the 16 lanes of each quad (cols 0..31 per tile)
#pragma unroll
  for (int r = 0; r < 4; ++r) {
#pragma unroll
    for (int mm = 1; mm < 16; mm <<= 1) lsum[r] += __shfl_xor(lsum[r], mm, 64);
  }
  float rl[4];
#pragma unroll
  for (int r = 0; r < 4; ++r) rl[r] = 1.0f / lsum[r];
#pragma unroll
  for (int vi = 0; vi < 4; ++vi) {
#pragma unroll
    for (int r = 0; r < 4; ++r) {
      size_t row = (size_t)b * 1024 + m0 + w * 16 + quad * 4 + r;
      out[row * 256 + h * 64 + vi * 16 + lo] = acc_o[vi][r] * rl[r];
    }
  }
}

// ---------------------------------------------------------------------------
extern "C" void kernel_launch(void* const* d_in, const int* in_sizes, int n_in,
                              void* d_out, int out_size, void* d_ws, size_t ws_size,
                              hipStream_t stream) {
  const float* first  = (const float*)d_in[0];
  const float* second = (const float*)d_in[1];
  const float* Wk = (const float*)d_in[2];
  const float* bk = (const float*)d_in[3];
  const float* Wq = (const float*)d_in[4];
  const float* bq = (const float*)d_in[5];
  const float* Wv = (const float*)d_in[6];
  const float* bv = (const float*)d_in[7];
  float* out = (float*)d_out;

  char* ws = (char*)d_ws;
  bf16* Afs  = (bf16*)(ws);
  bf16* Asnd = (bf16*)(ws + 205520896ULL);
  bf16* WkT  = (bf16*)(ws + 411041792ULL);
  bf16* WqT  = (bf16*)(ws + 436731904ULL);
  bf16* WvT  = (bf16*)(ws + 462422016ULL);
  bf16* Kw   = (bf16*)(ws + 468844544ULL);
  bf16* Qw   = (bf16*)(ws + 485621760ULL);
  bf16* Vw   = (bf16*)(ws + 502398976ULL);

  const int n4 = 102760448 / 4;  // 8192*12544 / 4
  cast_bf16_kernel<<<4096, 256, 0, stream>>>((const float4*)first, (bf16x4*)Afs, n4);
  cast_bf16_kernel<<<4096, 256, 0, stream>>>((const float4*)second, (bf16x4*)Asnd, n4);

  transpose_cast_kernel<<<dim3(196, 16), 256, 0, stream>>>(Wk, WkT, 1024);
  transpose_cast_kernel<<<dim3(196, 16), 256, 0, stream>>>(Wq, WqT, 1024);
  transpose_cast_kernel<<<dim3(196, 4), 256, 0, stream>>>(Wv, WvT, 256);

  // K and Q projections fused in one 256-block dispatch (1 block/CU).
  gemm_kq_kernel<<<dim3(32, 4, 2), 512, 0, stream>>>(Afs, Asnd, WkT, WqT, bk, bq,
                                                     Kw, Qw);
  gemm_bt_kernel<<<dim3(64, 2), 256, 0, stream>>>(Afs, WvT, bv, Vw, 256);

  normq_kernel<<<8192, 256, 0, stream>>>(Qw);

  attn_kernel<<<dim3(16, 4, 8), 256, 0, stream>>>(Qw, Kw, Vw, out);
}